// Round 2
// baseline (701.158 us; speedup 1.0000x reference)
//
#include <hip/hip_runtime.h>
#include <hip/hip_bf16.h>
#include <math.h>

// ---- problem constants ----
// N=2 T=8192 D=1024 H=16 DQ=DV=64 S=16 L=512
#define NT 16384        // N*T rows
#define DD 1024
#define QKVN 3072

typedef unsigned short u16;
typedef _Float16 half8 __attribute__((ext_vector_type(8)));
typedef float f32x4 __attribute__((ext_vector_type(4)));

#define DEV static __device__ __forceinline__

DEV float h2f(u16 u) { _Float16 h; __builtin_memcpy(&h, &u, 2); return (float)h; }
DEV u16 f2h(float f) { _Float16 h = (_Float16)f; u16 u; __builtin_memcpy(&u, &h, 2); return u; }
DEV f32x4 mfma16(half8 a, half8 b, f32x4 c) {
  return __builtin_amdgcn_mfma_f32_16x16x32_f16(a, b, c, 0, 0, 0);
}
DEV half8 ld8(const u16* p) { return *(const half8*)p; }
DEV float elu1(float x) { return x > 0.f ? x + 1.f : expf(x); }

// ---------------- weight transpose + cast (W[d][c] -> WT[c][d] fp16) ----------------
__global__ __launch_bounds__(256) void prep_w(const float* __restrict__ Wq,
    const float* __restrict__ Wk, const float* __restrict__ Wv,
    const float* __restrict__ Wo, u16* __restrict__ WqkvT, u16* __restrict__ WoT) {
  __shared__ float tile[64][65];
  const int mat = blockIdx.z;
  const float* src = mat == 0 ? Wq : mat == 1 ? Wk : mat == 2 ? Wv : Wo;
  const int d0 = blockIdx.x * 64, c0 = blockIdx.y * 64;
  const int t = threadIdx.x;
#pragma unroll
  for (int i = 0; i < 16; ++i) {
    int rl = (t >> 6) + i * 4;
    tile[rl][t & 63] = src[(size_t)(d0 + rl) * DD + c0 + (t & 63)];
  }
  __syncthreads();
  u16* dst = mat < 3 ? WqkvT + (size_t)mat * DD * DD : WoT;
#pragma unroll
  for (int i = 0; i < 16; ++i) {
    int cl = (t >> 6) + i * 4;
    dst[(size_t)(c0 + cl) * DD + d0 + (t & 63)] = f2h(tile[t & 63][cl]);
  }
}

__global__ void pack_bias(const float* __restrict__ bq, const float* __restrict__ bk,
                          const float* __restrict__ bv, float* __restrict__ bqkv) {
  int i = blockIdx.x * 256 + threadIdx.x;
  if (i < 1024) bqkv[i] = bq[i];
  else if (i < 2048) bqkv[i] = bk[i - 1024];
  else if (i < 3072) bqkv[i] = bv[i - 2048];
}

// ---------------- RoPE cos/sin table: tab[t][i] = (cos,sin)(t * 10000^(-i/32)) ----------------
__global__ __launch_bounds__(256) void rope_table(float* __restrict__ tab) {
  int idx = blockIdx.x * 256 + threadIdx.x;   // 8192*32
  int tp = idx >> 5, i = idx & 31;
  double inv = exp(-(double)i * (log(10000.0) / 32.0));
  double ang = (double)tp * inv;
  tab[idx * 2]     = (float)cos(ang);
  tab[idx * 2 + 1] = (float)sin(ang);
}

// ---------------- LayerNorm (fp32 in -> fp16 out) ----------------
__global__ __launch_bounds__(256) void lnorm(const float* __restrict__ x,
    const float* __restrict__ g, const float* __restrict__ b, u16* __restrict__ xn) {
  const int row = blockIdx.x, t = threadIdx.x;
  float4 v = ((const float4*)x)[(size_t)row * 256 + t];
  float s = v.x + v.y + v.z + v.w;
  float sq = v.x * v.x + v.y * v.y + v.z * v.z + v.w * v.w;
  for (int o = 32; o; o >>= 1) { s += __shfl_down(s, o); sq += __shfl_down(sq, o); }
  __shared__ float ps[4], pq[4];
  const int w = t >> 6, lane = t & 63;
  if (lane == 0) { ps[w] = s; pq[w] = sq; }
  __syncthreads();
  s = ps[0] + ps[1] + ps[2] + ps[3];
  sq = pq[0] + pq[1] + pq[2] + pq[3];
  float mu = s * (1.f / 1024.f);
  float var = sq * (1.f / 1024.f) - mu * mu;
  float rs = rsqrtf(var + 1e-5f);
  float4 gg = ((const float4*)g)[t], bb = ((const float4*)b)[t];
  float o0 = (v.x - mu) * rs * gg.x + bb.x;
  float o1 = (v.y - mu) * rs * gg.y + bb.y;
  float o2 = (v.z - mu) * rs * gg.z + bb.z;
  float o3 = (v.w - mu) * rs * gg.w + bb.w;
  uint2 u2;
  u2.x = (unsigned)f2h(o0) | ((unsigned)f2h(o1) << 16);
  u2.y = (unsigned)f2h(o2) | ((unsigned)f2h(o3) << 16);
  *(uint2*)&xn[(size_t)row * 1024 + t * 4] = u2;
}

// ---------------- GEMM: C[M,N] = A[M,K] @ BT[N,K]^T + bias ----------------
// fp16 inputs, fp32 accum, 128x128 tile, 4 waves (each 64x64), 16x16x32 MFMA.
template <bool OUT_F16>
__global__ __launch_bounds__(256) void gemm_bt(const u16* __restrict__ A,
    const u16* __restrict__ BT, const float* __restrict__ bias,
    void* __restrict__ C, int M, int N, int K) {
  __shared__ u16 As[128][40];   // +8 pad: 80B row stride, 16B aligned, 2-way-max banks
  __shared__ u16 Bs[128][40];
  const int t = threadIdx.x;
  const int lane = t & 63, w = t >> 6;
  const int wr = w >> 1, wc = w & 1;
  const int m0 = blockIdx.x * 128, n0 = blockIdx.y * 128;
  const int srow = t >> 2, kslot = t & 3;
  f32x4 acc[4][4] = {};
  for (int k0 = 0; k0 < K; k0 += 32) {
#pragma unroll
    for (int p = 0; p < 2; ++p) {
      int r = p * 64 + srow;
      uint4 a4 = *(const uint4*)&A[(size_t)(m0 + r) * K + k0 + kslot * 8];
      uint4 b4 = *(const uint4*)&BT[(size_t)(n0 + r) * K + k0 + kslot * 8];
      *(uint4*)&As[r][kslot * 8] = a4;
      *(uint4*)&Bs[r][kslot * 8] = b4;
    }
    __syncthreads();
    half8 af[4], bfr[4];
#pragma unroll
    for (int i = 0; i < 4; ++i) {
      af[i]  = ld8(&As[wr * 64 + i * 16 + (lane & 15)][(lane >> 4) * 8]);
      bfr[i] = ld8(&Bs[wc * 64 + i * 16 + (lane & 15)][(lane >> 4) * 8]);
    }
#pragma unroll
    for (int mi = 0; mi < 4; ++mi)
#pragma unroll
      for (int ni = 0; ni < 4; ++ni)
        acc[mi][ni] = mfma16(af[mi], bfr[ni], acc[mi][ni]);
    __syncthreads();
  }
  const int rg = lane >> 4, cl = lane & 15;
#pragma unroll
  for (int mi = 0; mi < 4; ++mi)
#pragma unroll
    for (int r = 0; r < 4; ++r) {
      size_t row = (size_t)(m0 + wr * 64 + mi * 16 + rg * 4 + r);
#pragma unroll
      for (int ni = 0; ni < 4; ++ni) {
        int col = n0 + wc * 64 + ni * 16 + cl;
        float v = acc[mi][ni][r] + bias[col];
        if (OUT_F16) ((u16*)C)[row * N + col] = f2h(v);
        else ((float*)C)[row * N + col] = v;
      }
    }
}

// ---------------- RoPE apply (in-place on q,k columns 0..2047 of qkv) ----------------
__global__ __launch_bounds__(256) void rope_apply(u16* __restrict__ qkv,
                                                  const float* __restrict__ tab) {
  const int row = blockIdx.x, t = threadIdx.x;
  const int c = t * 8;                 // 0..2047
  const int tp = row & 8191;
  const int d0 = c & 63;
  size_t off = (size_t)row * QKVN + c;
  union { uint4 v; u16 s[8]; } q;
  q.v = *(const uint4*)&qkv[off];
  float4 cs0 = *(const float4*)&tab[(tp * 32 + (d0 >> 1)) * 2];
  float4 cs1 = *(const float4*)&tab[(tp * 32 + (d0 >> 1)) * 2 + 4];
  float co[4] = {cs0.x, cs0.z, cs1.x, cs1.z};
  float si[4] = {cs0.y, cs0.w, cs1.y, cs1.w};
#pragma unroll
  for (int j = 0; j < 4; ++j) {
    float x0 = h2f(q.s[2 * j]), x1 = h2f(q.s[2 * j + 1]);
    q.s[2 * j]     = f2h(x0 * co[j] - x1 * si[j]);
    q.s[2 * j + 1] = f2h(x1 * co[j] + x0 * si[j]);
  }
  *(uint4*)&qkv[off] = q.v;
}

// ---------------- per-segment stats: Mseg[d][e] = sum_l sk[l][d] v[l][e]; Zseg[d] ----------------
__global__ __launch_bounds__(256) void segstats(const u16* __restrict__ qkv,
    float* __restrict__ Mseg, float* __restrict__ Zseg) {
  __shared__ float skL[128][64];
  __shared__ float vL[128][64];
  const int b = blockIdx.x;            // (n*16+h)*16+seg
  const int seg = b & 15, h = (b >> 4) & 15, n = b >> 8;
  const int t = threadIdx.x;
  const int d = t >> 2, e0 = (t & 3) * 16;
  float acc[16] = {};
  float zacc = 0.f;
  const size_t base = (size_t)(n * 8192 + seg * 512) * QKVN;
  for (int ch = 0; ch < 4; ++ch) {
#pragma unroll
    for (int p = 0; p < 4; ++p) {
      int r = (t >> 3) + 32 * p;
      int cs = (t & 7) * 8;
      size_t ro = base + (size_t)(ch * 128 + r) * QKVN + h * 64 + cs;
      union { uint4 v; u16 s[8]; } kk, vv;
      kk.v = *(const uint4*)&qkv[ro + 1024];
      vv.v = *(const uint4*)&qkv[ro + 2048];
#pragma unroll
      for (int j = 0; j < 8; ++j) {
        skL[r][cs + j] = elu1(h2f(kk.s[j]));
        vL[r][cs + j] = h2f(vv.s[j]);
      }
    }
    __syncthreads();
    for (int l = 0; l < 128; ++l) {
      float s = skL[l][d];
      zacc += s;
      const float4* vr = (const float4*)&vL[l][e0];
      float4 a0 = vr[0], a1 = vr[1], a2 = vr[2], a3 = vr[3];
      acc[0] += s * a0.x;  acc[1] += s * a0.y;  acc[2] += s * a0.z;  acc[3] += s * a0.w;
      acc[4] += s * a1.x;  acc[5] += s * a1.y;  acc[6] += s * a1.z;  acc[7] += s * a1.w;
      acc[8] += s * a2.x;  acc[9] += s * a2.y;  acc[10] += s * a2.z; acc[11] += s * a2.w;
      acc[12] += s * a3.x; acc[13] += s * a3.y; acc[14] += s * a3.z; acc[15] += s * a3.w;
    }
    __syncthreads();
  }
  size_t mb = (size_t)b * 4096 + d * 64 + e0;
  float4 o0 = {acc[0], acc[1], acc[2], acc[3]};
  float4 o1 = {acc[4], acc[5], acc[6], acc[7]};
  float4 o2 = {acc[8], acc[9], acc[10], acc[11]};
  float4 o3 = {acc[12], acc[13], acc[14], acc[15]};
  *(float4*)&Mseg[mb] = o0; *(float4*)&Mseg[mb + 4] = o1;
  *(float4*)&Mseg[mb + 8] = o2; *(float4*)&Mseg[mb + 12] = o3;
  if ((t & 3) == 0) Zseg[(size_t)b * 64 + d] = zacc;
}

// ---------------- exclusive prefix over segments ----------------
__global__ __launch_bounds__(256) void prefix_k(const float* __restrict__ Mseg,
    const float* __restrict__ Zseg, float* __restrict__ Mpre, float* __restrict__ Zpre) {
  const int nh = blockIdx.x;           // 0..31
  const int t = threadIdx.x;
#pragma unroll
  for (int p = 0; p < 4; ++p) {
    int f4 = (t + 256 * p) * 4;
    float4 acc = {0.f, 0.f, 0.f, 0.f};
    for (int s = 0; s < 16; ++s) {
      size_t idx = (size_t)(nh * 16 + s) * 4096 + f4;
      *(float4*)&Mpre[idx] = acc;
      float4 m = *(const float4*)&Mseg[idx];
      acc.x += m.x; acc.y += m.y; acc.z += m.z; acc.w += m.w;
    }
  }
  if (t < 16) {
    float4 acc = {0.f, 0.f, 0.f, 0.f};
    for (int s = 0; s < 16; ++s) {
      size_t idx = (size_t)(nh * 16 + s) * 64 + t * 4;
      *(float4*)&Zpre[idx] = acc;
      float4 z = *(const float4*)&Zseg[idx];
      acc.x += z.x; acc.y += z.y; acc.z += z.z; acc.w += z.w;
    }
  }
}

// ---------------- fused per-segment attention + memory-read + combine ----------------
struct SmemA { u16 Ks[64][88]; u16 VTs[64][88]; u16 Ps[64][88]; };
struct SmemB { float outL[64][68]; float MpL[64][68]; float sqL[64][68]; };
union SmemU { SmemA a; SmemB b; };

__global__ __launch_bounds__(256) void attn_seg(const u16* __restrict__ qkv,
    const float* __restrict__ Mpre, const float* __restrict__ Zpre,
    const float* __restrict__ beta, u16* __restrict__ ao) {
  __shared__ __align__(16) u16 Qs[64][88];
  __shared__ __align__(16) SmemU U;
  const int b = blockIdx.x;
  const int qt = b & 7, seg = (b >> 3) & 15, h = (b >> 7) & 15, n = b >> 11;
  const int t = threadIdx.x, lane = t & 63, w = t >> 6;

  // stage Q tile (64 rows x 64 d)
  const size_t qbase = (size_t)(n * 8192 + seg * 512 + qt * 64) * QKVN + h * 64;
#pragma unroll
  for (int p = 0; p < 2; ++p) {
    int r = p * 32 + (t >> 3), cs = (t & 7) * 8;
    *(uint4*)&Qs[r][cs] = *(const uint4*)&qkv[qbase + (size_t)r * QKVN + cs];
  }

  float mrow[4], lrow[4];
  f32x4 oacc[4] = {};
#pragma unroll
  for (int r = 0; r < 4; ++r) { mrow[r] = -INFINITY; lrow[r] = 0.f; }

  const size_t kbase = (size_t)(n * 8192 + seg * 512) * QKVN + h * 64;
  for (int mt = 0; mt <= qt; ++mt) {
#pragma unroll
    for (int p = 0; p < 2; ++p) {
      int r = p * 32 + (t >> 3), cs = (t & 7) * 8;
      size_t ro = kbase + (size_t)(mt * 64 + r) * QKVN;
      *(uint4*)&U.a.Ks[r][cs] = *(const uint4*)&qkv[ro + 1024 + cs];
      union { uint4 v; u16 s[8]; } vv;
      vv.v = *(const uint4*)&qkv[ro + 2048 + cs];
#pragma unroll
      for (int j = 0; j < 8; ++j) U.a.VTs[cs + j][r] = vv.s[j];   // V^T
    }
    __syncthreads();
    // S = Q K^T (per wave: 16 q rows x 64 m cols)
    half8 aq0 = ld8(&Qs[w * 16 + (lane & 15)][(lane >> 4) * 8]);
    half8 aq1 = ld8(&Qs[w * 16 + (lane & 15)][32 + (lane >> 4) * 8]);
    f32x4 s[4] = {};
#pragma unroll
    for (int ni = 0; ni < 4; ++ni) {
      half8 b0 = ld8(&U.a.Ks[ni * 16 + (lane & 15)][(lane >> 4) * 8]);
      half8 b1 = ld8(&U.a.Ks[ni * 16 + (lane & 15)][32 + (lane >> 4) * 8]);
      s[ni] = mfma16(aq0, b0, s[ni]);
      s[ni] = mfma16(aq1, b1, s[ni]);
    }
    // scale + causal mask + online softmax
    float pm[4];
#pragma unroll
    for (int r = 0; r < 4; ++r) {
      int ql = qt * 64 + w * 16 + (lane >> 4) * 4 + r;
      float mx = -INFINITY;
#pragma unroll
      for (int ni = 0; ni < 4; ++ni) {
        float v = s[ni][r] * 0.125f;
        if (mt == qt) { int ml = mt * 64 + ni * 16 + (lane & 15); if (ml > ql) v = -INFINITY; }
        s[ni][r] = v; mx = fmaxf(mx, v);
      }
      pm[r] = mx;
    }
#pragma unroll
    for (int o = 1; o < 16; o <<= 1)
#pragma unroll
      for (int r = 0; r < 4; ++r) pm[r] = fmaxf(pm[r], __shfl_xor(pm[r], o, 16));
    float fac[4], rs[4];
#pragma unroll
    for (int r = 0; r < 4; ++r) {
      float mn = fmaxf(mrow[r], pm[r]);
      fac[r] = expf(mrow[r] - mn);
      mrow[r] = mn;
      float a = 0.f;
#pragma unroll
      for (int ni = 0; ni < 4; ++ni) { float p = expf(s[ni][r] - mn); s[ni][r] = p; a += p; }
      rs[r] = a;
    }
#pragma unroll
    for (int o = 1; o < 16; o <<= 1)
#pragma unroll
      for (int r = 0; r < 4; ++r) rs[r] += __shfl_xor(rs[r], o, 16);
#pragma unroll
    for (int r = 0; r < 4; ++r) {
      lrow[r] = lrow[r] * fac[r] + rs[r];
#pragma unroll
      for (int ei = 0; ei < 4; ++ei) oacc[ei][r] *= fac[r];
    }
    // P -> LDS (re-layout for A-operand of PV)
#pragma unroll
    for (int ni = 0; ni < 4; ++ni)
#pragma unroll
      for (int r = 0; r < 4; ++r)
        U.a.Ps[w * 16 + (lane >> 4) * 4 + r][ni * 16 + (lane & 15)] = f2h(s[ni][r]);
    __syncthreads();
    // O += P @ V
#pragma unroll
    for (int ks = 0; ks < 2; ++ks) {
      half8 ap = ld8(&U.a.Ps[w * 16 + (lane & 15)][ks * 32 + (lane >> 4) * 8]);
#pragma unroll
      for (int ei = 0; ei < 4; ++ei) {
        half8 bv = ld8(&U.a.VTs[ei * 16 + (lane & 15)][ks * 32 + (lane >> 4) * 8]);
        oacc[ei] = mfma16(ap, bv, oacc[ei]);
      }
    }
    __syncthreads();
  }
  // normalize + park local output in LDS
#pragma unroll
  for (int ei = 0; ei < 4; ++ei)
#pragma unroll
    for (int r = 0; r < 4; ++r)
      U.b.outL[w * 16 + (lane >> 4) * 4 + r][ei * 16 + (lane & 15)] = oacc[ei][r] / lrow[r];
  // stage Mpre and sq = elu(Q)+1
  const size_t mpb = (size_t)((n * 16 + h) * 16 + seg) * 4096;
#pragma unroll
  for (int p = 0; p < 4; ++p) {
    int d = p * 16 + (t >> 4), e0 = (t & 15) * 4;
    *(float4*)&U.b.MpL[d][e0] = *(const float4*)&Mpre[mpb + d * 64 + e0];
  }
#pragma unroll
  for (int p = 0; p < 4; ++p) {
    int r = p * 16 + (t >> 4), c0 = (t & 15) * 4;
    union { uint2 v; u16 s[4]; } qq;
    qq.v = *(const uint2*)&Qs[r][c0];
    float4 sv;
    sv.x = elu1(h2f(qq.s[0])); sv.y = elu1(h2f(qq.s[1]));
    sv.z = elu1(h2f(qq.s[2])); sv.w = elu1(h2f(qq.s[3]));
    *(float4*)&U.b.sqL[r][c0] = sv;
  }
  __syncthreads();
  // combine: out = gb * (sq@Mpre)/(rowsum(sq)*Zpre + 1e-6) + (1-gb) * local
  const int q = t >> 2, e0 = (t & 3) * 16;
  float accM[16] = {};
  float rowsum = 0.f;
  for (int d = 0; d < 64; ++d) {
    float s = U.b.sqL[q][d];
    rowsum += s;
    const float4* mr = (const float4*)&U.b.MpL[d][e0];
    float4 a0 = mr[0], a1 = mr[1], a2 = mr[2], a3 = mr[3];
    accM[0] += s * a0.x;  accM[1] += s * a0.y;  accM[2] += s * a0.z;  accM[3] += s * a0.w;
    accM[4] += s * a1.x;  accM[5] += s * a1.y;  accM[6] += s * a1.z;  accM[7] += s * a1.w;
    accM[8] += s * a2.x;  accM[9] += s * a2.y;  accM[10] += s * a2.z; accM[11] += s * a2.w;
    accM[12] += s * a3.x; accM[13] += s * a3.y; accM[14] += s * a3.z; accM[15] += s * a3.w;
  }
  const float gb = 1.f / (1.f + expf(-beta[0]));
  const size_t zb = (size_t)((n * 16 + h) * 16 + seg) * 64 + e0;
  float z[16];
#pragma unroll
  for (int j4 = 0; j4 < 4; ++j4) {
    float4 zz = *(const float4*)&Zpre[zb + j4 * 4];
    z[j4 * 4] = zz.x; z[j4 * 4 + 1] = zz.y; z[j4 * 4 + 2] = zz.z; z[j4 * 4 + 3] = zz.w;
  }
  union { uint4 v[2]; u16 s[16]; } ov;
#pragma unroll
  for (int j = 0; j < 16; ++j) {
    float denom = rowsum * z[j] + 1e-6f;
    float am = accM[j] / denom;
    float loc = U.b.outL[q][e0 + j];
    ov.s[j] = f2h(gb * am + (1.f - gb) * loc);
  }
  // scrambled output layout: t = seg*512 + h*32 + (l>>4), c = (l&15)*64 + e, l = qt*64+q
  const size_t row = (size_t)(n * 8192 + seg * 512 + h * 32 + qt * 4 + (q >> 4));
  const size_t col = (size_t)(q & 15) * 64 + e0;
  *(uint4*)&ao[row * 1024 + col] = ov.v[0];
  *(uint4*)&ao[row * 1024 + col + 8] = ov.v[1];
}

// ---------------- launch ----------------
extern "C" void kernel_launch(void* const* d_in, const int* in_sizes, int n_in,
                              void* d_out, int out_size, void* d_ws, size_t ws_size,
                              hipStream_t stream) {
  const float* x    = (const float*)d_in[0];
  const float* ln_g = (const float*)d_in[1];
  const float* ln_b = (const float*)d_in[2];
  const float* Wq   = (const float*)d_in[3];
  const float* bq   = (const float*)d_in[4];
  const float* Wk   = (const float*)d_in[5];
  const float* bk   = (const float*)d_in[6];
  const float* Wv   = (const float*)d_in[7];
  const float* bv   = (const float*)d_in[8];
  const float* Wo   = (const float*)d_in[9];
  const float* bo   = (const float*)d_in[10];
  const float* beta = (const float*)d_in[11];
  float* out = (float*)d_out;

  char* w = (char*)d_ws;
  u16*   xn    = (u16*)(w + 0);               // 32 MB
  u16*   qkv   = (u16*)(w + 33554432ull);     // 96 MB
  u16*   WqkvT = (u16*)(w + 134217728ull);    // 6 MB
  u16*   WoT   = (u16*)(w + 140509184ull);    // 2 MB
  float* bqkv  = (float*)(w + 142606336ull);  // 12 KB
  float* tab   = (float*)(w + 142618624ull);  // 2 MB
  float* Mseg  = (float*)(w + 144715776ull);  // 8 MB
  float* Zseg  = (float*)(w + 153104384ull);  // 128 KB
  float* Mpre  = (float*)(w + 153235456ull);  // 8 MB
  float* Zpre  = (float*)(w + 161624064ull);  // 128 KB
  u16*   ao    = (u16*)(w + 161755136ull);    // 32 MB   (total ~186 MB)

  prep_w<<<dim3(16, 16, 4), 256, 0, stream>>>(Wq, Wk, Wv, Wo, WqkvT, WoT);
  pack_bias<<<12, 256, 0, stream>>>(bq, bk, bv, bqkv);
  rope_table<<<1024, 256, 0, stream>>>(tab);
  lnorm<<<16384, 256, 0, stream>>>(x, ln_g, ln_b, xn);
  gemm_bt<true><<<dim3(128, 24), 256, 0, stream>>>(xn, WqkvT, bqkv, (void*)qkv, NT, QKVN, DD);
  rope_apply<<<16384, 256, 0, stream>>>(qkv, tab);
  segstats<<<512, 256, 0, stream>>>(qkv, Mseg, Zseg);
  prefix_k<<<32, 256, 0, stream>>>(Mseg, Zseg, Mpre, Zpre);
  attn_seg<<<4096, 256, 0, stream>>>(qkv, Mpre, Zpre, beta, ao);
  gemm_bt<false><<<dim3(128, 8), 256, 0, stream>>>(ao, WoT, bo, (void*)out, NT, DD, DD);
}

// Round 5
// 524.929 us; speedup vs baseline: 1.3357x; 1.3357x over previous
//
#include <hip/hip_runtime.h>
#include <hip/hip_bf16.h>
#include <math.h>

// ---- problem constants ----
// N=2 T=8192 D=1024 H=16 DQ=DV=64 S=16 L=512
#define NT 16384        // N*T rows
#define DD 1024
#define QKVN 3072

typedef unsigned short u16;
typedef _Float16 half8 __attribute__((ext_vector_type(8)));
typedef float f32x4 __attribute__((ext_vector_type(4)));

#define DEV static __device__ __forceinline__

DEV float h2f(u16 u) { _Float16 h; __builtin_memcpy(&h, &u, 2); return (float)h; }
DEV u16 f2h(float f) { _Float16 h = (_Float16)f; u16 u; __builtin_memcpy(&u, &h, 2); return u; }
DEV f32x4 mfma16(half8 a, half8 b, f32x4 c) {
  return __builtin_amdgcn_mfma_f32_16x16x32_f16(a, b, c, 0, 0, 0);
}
DEV half8 ld8(const u16* p) { return *(const half8*)p; }
DEV float elu1(float x) { return x > 0.f ? x + 1.f : __expf(x); }
DEV void gll16(const void* g, void* l) {
  __builtin_amdgcn_global_load_lds((const __attribute__((address_space(1))) void*)g,
                                   (__attribute__((address_space(3))) void*)l, 16, 0, 0);
}

// ---------------- weight transpose + cast (W[d][c] -> WT[c][d] fp16) ----------------
__global__ __launch_bounds__(256) void prep_w(const float* __restrict__ Wq,
    const float* __restrict__ Wk, const float* __restrict__ Wv,
    const float* __restrict__ Wo, u16* __restrict__ WqkvT, u16* __restrict__ WoT) {
  __shared__ float tile[64][65];
  const int mat = blockIdx.z;
  const float* src = mat == 0 ? Wq : mat == 1 ? Wk : mat == 2 ? Wv : Wo;
  const int d0 = blockIdx.x * 64, c0 = blockIdx.y * 64;
  const int t = threadIdx.x;
#pragma unroll
  for (int i = 0; i < 16; ++i) {
    int rl = (t >> 6) + i * 4;
    tile[rl][t & 63] = src[(size_t)(d0 + rl) * DD + c0 + (t & 63)];
  }
  __syncthreads();
  u16* dst = mat < 3 ? WqkvT + (size_t)mat * DD * DD : WoT;
#pragma unroll
  for (int i = 0; i < 16; ++i) {
    int cl = (t >> 6) + i * 4;
    dst[(size_t)(c0 + cl) * DD + d0 + (t & 63)] = f2h(tile[t & 63][cl]);
  }
}

__global__ void pack_bias(const float* __restrict__ bq, const float* __restrict__ bk,
                          const float* __restrict__ bv, float* __restrict__ bqkv) {
  int i = blockIdx.x * 256 + threadIdx.x;
  if (i < 1024) bqkv[i] = bq[i];
  else if (i < 2048) bqkv[i] = bk[i - 1024];
  else if (i < 3072) bqkv[i] = bv[i - 2048];
}

// ---------------- RoPE cos/sin table ----------------
__global__ __launch_bounds__(256) void rope_table(float* __restrict__ tab) {
  int idx = blockIdx.x * 256 + threadIdx.x;   // 8192*32
  int tp = idx >> 5, i = idx & 31;
  double inv = exp(-(double)i * (log(10000.0) / 32.0));
  double ang = (double)tp * inv;
  tab[idx * 2]     = (float)cos(ang);
  tab[idx * 2 + 1] = (float)sin(ang);
}

// ---------------- LayerNorm (fp32 in -> fp16 out) ----------------
__global__ __launch_bounds__(256) void lnorm(const float* __restrict__ x,
    const float* __restrict__ g, const float* __restrict__ b, u16* __restrict__ xn) {
  const int row = blockIdx.x, t = threadIdx.x;
  float4 v = ((const float4*)x)[(size_t)row * 256 + t];
  float s = v.x + v.y + v.z + v.w;
  float sq = v.x * v.x + v.y * v.y + v.z * v.z + v.w * v.w;
  for (int o = 32; o; o >>= 1) { s += __shfl_down(s, o); sq += __shfl_down(sq, o); }
  __shared__ float ps[4], pq[4];
  const int w = t >> 6, lane = t & 63;
  if (lane == 0) { ps[w] = s; pq[w] = sq; }
  __syncthreads();
  s = ps[0] + ps[1] + ps[2] + ps[3];
  sq = pq[0] + pq[1] + pq[2] + pq[3];
  float mu = s * (1.f / 1024.f);
  float var = sq * (1.f / 1024.f) - mu * mu;
  float rs = rsqrtf(var + 1e-5f);
  float4 gg = ((const float4*)g)[t], bb = ((const float4*)b)[t];
  float o0 = (v.x - mu) * rs * gg.x + bb.x;
  float o1 = (v.y - mu) * rs * gg.y + bb.y;
  float o2 = (v.z - mu) * rs * gg.z + bb.z;
  float o3 = (v.w - mu) * rs * gg.w + bb.w;
  uint2 u2;
  u2.x = (unsigned)f2h(o0) | ((unsigned)f2h(o1) << 16);
  u2.y = (unsigned)f2h(o2) | ((unsigned)f2h(o3) << 16);
  *(uint2*)&xn[(size_t)row * 1024 + t * 4] = u2;
}

// ---------------- GEMM: C[M,N] = A[M,K] @ BT[N,K]^T + bias (m97 structure) ----------------
// global_load_lds width-16 staging, linear [128][32] LDS, chunk-XOR swizzle (rule #21:
// pre-swizzled global source + swizzled ds_read; LDS dest stays lane-linear).
template <bool OUT_F16>
__global__ __launch_bounds__(256) void gemm_bt(const u16* __restrict__ A,
    const u16* __restrict__ BT, const float* __restrict__ bias,
    void* __restrict__ C, int M, int N, int K) {
  __shared__ u16 As[128 * 32];
  __shared__ u16 Bs[128 * 32];
  const int t = threadIdx.x;
  const int lane = t & 63, w = t >> 6;
  const int wr = w >> 1, wc = w & 1;
  const int m0 = blockIdx.x * 128, n0 = blockIdx.y * 128;
  // staging assignment: issue i covers local rows i*64 + w*16 .. +15; lane -> (row, chunk)
  const int srow = w * 16 + (lane >> 2);     // + i*64
  const int schunk = lane & 3;
  // frag read offsets (loop-invariant): global chunk g=lane>>4 of row ra lives at
  // LDS chunk g ^ ((ra>>1)&3)
  int aoff[4], boff[4];
#pragma unroll
  for (int i = 0; i < 4; ++i) {
    int ra = wr * 64 + i * 16 + (lane & 15);
    aoff[i] = ra * 32 + (((lane >> 4) ^ ((ra >> 1) & 3)) * 8);
    int rb = wc * 64 + i * 16 + (lane & 15);
    boff[i] = rb * 32 + (((lane >> 4) ^ ((rb >> 1) & 3)) * 8);
  }
  f32x4 acc[4][4] = {};
  for (int k0 = 0; k0 < K; k0 += 32) {
#pragma unroll
    for (int i = 0; i < 2; ++i) {
      int row = srow + i * 64;
      int gc = (schunk ^ ((row >> 1) & 3)) * 8;   // pre-swizzled global source chunk
      gll16(&A[(size_t)(m0 + row) * K + k0 + gc], &As[(w * 16 + i * 64) * 32]);
      gll16(&BT[(size_t)(n0 + row) * K + k0 + gc], &Bs[(w * 16 + i * 64) * 32]);
    }
    __syncthreads();
    half8 af[4], bfr[4];
#pragma unroll
    for (int i = 0; i < 4; ++i) {
      af[i]  = ld8(&As[aoff[i]]);
      bfr[i] = ld8(&Bs[boff[i]]);
    }
#pragma unroll
    for (int mi = 0; mi < 4; ++mi)
#pragma unroll
      for (int ni = 0; ni < 4; ++ni)
        acc[mi][ni] = mfma16(af[mi], bfr[ni], acc[mi][ni]);
    __syncthreads();
  }
  const int rg = lane >> 4, cl = lane & 15;
#pragma unroll
  for (int mi = 0; mi < 4; ++mi)
#pragma unroll
    for (int r = 0; r < 4; ++r) {
      size_t row = (size_t)(m0 + wr * 64 + mi * 16 + rg * 4 + r);
#pragma unroll
      for (int ni = 0; ni < 4; ++ni) {
        int col = n0 + wc * 64 + ni * 16 + cl;
        float v = acc[mi][ni][r] + bias[col];
        if (OUT_F16) ((u16*)C)[row * N + col] = f2h(v);
        else ((float*)C)[row * N + col] = v;
      }
    }
}

// ---------------- RoPE apply (in-place on q,k columns 0..2047 of qkv) ----------------
__global__ __launch_bounds__(256) void rope_apply(u16* __restrict__ qkv,
                                                  const float* __restrict__ tab) {
  const int row = blockIdx.x, t = threadIdx.x;
  const int c = t * 8;                 // 0..2047
  const int tp = row & 8191;
  const int d0 = c & 63;
  size_t off = (size_t)row * QKVN + c;
  union { uint4 v; u16 s[8]; } q;
  q.v = *(const uint4*)&qkv[off];
  float4 cs0 = *(const float4*)&tab[(tp * 32 + (d0 >> 1)) * 2];
  float4 cs1 = *(const float4*)&tab[(tp * 32 + (d0 >> 1)) * 2 + 4];
  float co[4] = {cs0.x, cs0.z, cs1.x, cs1.z};
  float si[4] = {cs0.y, cs0.w, cs1.y, cs1.w};
#pragma unroll
  for (int j = 0; j < 4; ++j) {
    float x0 = h2f(q.s[2 * j]), x1 = h2f(q.s[2 * j + 1]);
    q.s[2 * j]     = f2h(x0 * co[j] - x1 * si[j]);
    q.s[2 * j + 1] = f2h(x1 * co[j] + x0 * si[j]);
  }
  *(uint4*)&qkv[off] = q.v;
}

// ---------------- per-segment stats: Mseg[d][e] = sum_l sk[l][d] v[l][e]; Zseg[d] ----------------
__global__ __launch_bounds__(256) void segstats(const u16* __restrict__ qkv,
    float* __restrict__ Mseg, float* __restrict__ Zseg) {
  __shared__ float skL[128][64];
  __shared__ float vL[128][64];
  const int b = blockIdx.x;            // (n*16+h)*16+seg
  const int seg = b & 15, h = (b >> 4) & 15, n = b >> 8;
  const int t = threadIdx.x;
  const int d = t >> 2, e0 = (t & 3) * 16;
  float acc[16] = {};
  float zacc = 0.f;
  const size_t base = (size_t)(n * 8192 + seg * 512) * QKVN;
  for (int ch = 0; ch < 4; ++ch) {
#pragma unroll
    for (int p = 0; p < 4; ++p) {
      int r = (t >> 3) + 32 * p;
      int cs = (t & 7) * 8;
      size_t ro = base + (size_t)(ch * 128 + r) * QKVN + h * 64 + cs;
      union { uint4 v; u16 s[8]; } kk, vv;
      kk.v = *(const uint4*)&qkv[ro + 1024];
      vv.v = *(const uint4*)&qkv[ro + 2048];
#pragma unroll
      for (int j = 0; j < 8; ++j) {
        skL[r][cs + j] = elu1(h2f(kk.s[j]));
        vL[r][cs + j] = h2f(vv.s[j]);
      }
    }
    __syncthreads();
    for (int l = 0; l < 128; ++l) {
      float s = skL[l][d];
      zacc += s;
      const float4* vr = (const float4*)&vL[l][e0];
      float4 a0 = vr[0], a1 = vr[1], a2 = vr[2], a3 = vr[3];
      acc[0] += s * a0.x;  acc[1] += s * a0.y;  acc[2] += s * a0.z;  acc[3] += s * a0.w;
      acc[4] += s * a1.x;  acc[5] += s * a1.y;  acc[6] += s * a1.z;  acc[7] += s * a1.w;
      acc[8] += s * a2.x;  acc[9] += s * a2.y;  acc[10] += s * a2.z; acc[11] += s * a2.w;
      acc[12] += s * a3.x; acc[13] += s * a3.y; acc[14] += s * a3.z; acc[15] += s * a3.w;
    }
    __syncthreads();
  }
  size_t mb = (size_t)b * 4096 + d * 64 + e0;
  float4 o0 = {acc[0], acc[1], acc[2], acc[3]};
  float4 o1 = {acc[4], acc[5], acc[6], acc[7]};
  float4 o2 = {acc[8], acc[9], acc[10], acc[11]};
  float4 o3 = {acc[12], acc[13], acc[14], acc[15]};
  *(float4*)&Mseg[mb] = o0; *(float4*)&Mseg[mb + 4] = o1;
  *(float4*)&Mseg[mb + 8] = o2; *(float4*)&Mseg[mb + 12] = o3;
  if ((t & 3) == 0) Zseg[(size_t)b * 64 + d] = zacc;
}

// ---------------- exclusive prefix over segments; M output TRANSPOSED fp16 [b][e][d] ----------------
__global__ __launch_bounds__(256) void prefix_k(const float* __restrict__ Mseg,
    const float* __restrict__ Zseg, u16* __restrict__ MpT, float* __restrict__ Zpre) {
  const int nh = blockIdx.x;           // 0..31
  const int t = threadIdx.x;
  const int e = t >> 2, d0 = (t & 3) * 16;
  float acc[16] = {};
  for (int s = 0; s < 16; ++s) {
    size_t bb = (size_t)(nh * 16 + s) * 4096;
    union { uint4 v[2]; u16 hh[16]; } o;
#pragma unroll
    for (int j = 0; j < 16; ++j) o.hh[j] = f2h(acc[j]);
    *(uint4*)&MpT[bb + e * 64 + d0] = o.v[0];
    *(uint4*)&MpT[bb + e * 64 + d0 + 8] = o.v[1];
#pragma unroll
    for (int j = 0; j < 16; ++j) acc[j] += Mseg[bb + (size_t)(d0 + j) * 64 + e];
  }
  if (t < 16) {
    float4 zac = {0.f, 0.f, 0.f, 0.f};
    for (int s = 0; s < 16; ++s) {
      size_t idx = (size_t)(nh * 16 + s) * 64 + t * 4;
      *(float4*)&Zpre[idx] = zac;
      float4 z = *(const float4*)&Zseg[idx];
      zac.x += z.x; zac.y += z.y; zac.z += z.z; zac.w += z.w;
    }
  }
}

// ---------------- fused per-segment attention + memory-read + combine ----------------
// Per block: (n,h,seg,qt) -> 64 q-rows. 4 waves, each 16 q-rows.
// K/V reg-prefetch (T14); VT chunk-XOR swizzle; MFMA combine epilogue.
struct SmemA { u16 Ks[64][72]; u16 VTs[64][72]; u16 Ps[64][72]; };   // 27.6 KB
struct SmemB { u16 sqH[64][72]; u16 MpTs[64][72]; float rowS[64]; }; // 18.7 KB
union SmemU { SmemA a; SmemB b; };

__global__ __launch_bounds__(256, 3) void attn_seg(const u16* __restrict__ qkv,
    const u16* __restrict__ MpT, const float* __restrict__ Zpre,
    const float* __restrict__ beta, u16* __restrict__ ao) {
  __shared__ __align__(16) u16 Qs[64][72];
  __shared__ __align__(16) SmemU U;
  // XCD-chunked swizzle: 8 qt-blocks of a segment land on one XCD (K/V L2 reuse)
  const int b = (blockIdx.x & 7) * 512 + (blockIdx.x >> 3);
  const int qt = b & 7, seg = (b >> 3) & 15, h = (b >> 7) & 15, n = b >> 11;
  const int t = threadIdx.x, lane = t & 63, w = t >> 6;

  // stage Q tile (64 rows x 64 d)
  const size_t qbase = (size_t)(n * 8192 + seg * 512 + qt * 64) * QKVN + h * 64;
#pragma unroll
  for (int p = 0; p < 2; ++p) {
    int r = p * 32 + (t >> 3), cs = (t & 7) * 8;
    *(uint4*)&Qs[r][cs] = *(const uint4*)&qkv[qbase + (size_t)r * QKVN + cs];
  }

  // staging geometry (per thread, loop-invariant)
  const int r0 = t >> 3;               // k/v row (first half), +32 for second
  const int cs = (t & 7) * 8;          // d-chunk base
  const int vcol1 = (((w) ^ (t & 7)) << 3) | (r0 & 7);       // swizzled VT col for l=r0
  const int vcol2 = (((w + 4) ^ (t & 7)) << 3) | (r0 & 7);   // for l=r0+32
  const size_t kbase = (size_t)(n * 8192 + seg * 512) * QKVN + h * 64 + cs;

  // prefetch K/V tile 0
  uint4 kk0, kk1, vv0, vv1;
  {
    size_t ro = kbase + (size_t)r0 * QKVN;
    kk0 = *(const uint4*)&qkv[ro + 1024];
    vv0 = *(const uint4*)&qkv[ro + 2048];
    kk1 = *(const uint4*)&qkv[ro + 32 * QKVN + 1024];
    vv1 = *(const uint4*)&qkv[ro + 32 * QKVN + 2048];
  }
  __syncthreads();   // Qs visible
  // hoisted Q A-frags (16 q-rows per wave)
  half8 aq0 = ld8(&Qs[w * 16 + (lane & 15)][(lane >> 4) * 8]);
  half8 aq1 = ld8(&Qs[w * 16 + (lane & 15)][32 + (lane >> 4) * 8]);

  float mrow[4], lrow[4];
  f32x4 oacc[4] = {};
#pragma unroll
  for (int r = 0; r < 4; ++r) { mrow[r] = -INFINITY; lrow[r] = 0.f; }

  for (int mt = 0; mt <= qt; ++mt) {
    // write staged regs to LDS (K row-major; V transposed with chunk-XOR swizzle)
    *(uint4*)&U.a.Ks[r0][cs] = kk0;
    *(uint4*)&U.a.Ks[r0 + 32][cs] = kk1;
    union { uint4 v; u16 s[8]; } u0, u1;
    u0.v = vv0; u1.v = vv1;
#pragma unroll
    for (int j = 0; j < 8; ++j) {
      U.a.VTs[cs + j][vcol1] = u0.s[j];
      U.a.VTs[cs + j][vcol2] = u1.s[j];
    }
    if (mt < qt) {   // prefetch next tile (hides HBM latency under compute)
      size_t ro = kbase + (size_t)((mt + 1) * 64 + r0) * QKVN;
      kk0 = *(const uint4*)&qkv[ro + 1024];
      vv0 = *(const uint4*)&qkv[ro + 2048];
      kk1 = *(const uint4*)&qkv[ro + 32 * QKVN + 1024];
      vv1 = *(const uint4*)&qkv[ro + 32 * QKVN + 2048];
    }
    __syncthreads();   // staged K/VT visible

    // S = Q K^T (per wave: 16 q rows x 64 m cols)
    f32x4 s[4] = {};
#pragma unroll
    for (int ni = 0; ni < 4; ++ni) {
      half8 b0 = ld8(&U.a.Ks[ni * 16 + (lane & 15)][(lane >> 4) * 8]);
      half8 b1 = ld8(&U.a.Ks[ni * 16 + (lane & 15)][32 + (lane >> 4) * 8]);
      s[ni] = mfma16(aq0, b0, s[ni]);
      s[ni] = mfma16(aq1, b1, s[ni]);
    }
    // scale + causal mask + online softmax
    float pm[4];
#pragma unroll
    for (int r = 0; r < 4; ++r) {
      int ql = qt * 64 + w * 16 + (lane >> 4) * 4 + r;
      float mx = -INFINITY;
#pragma unroll
      for (int ni = 0; ni < 4; ++ni) {
        float v = s[ni][r] * 0.125f;
        if (mt == qt) { int ml = mt * 64 + ni * 16 + (lane & 15); if (ml > ql) v = -INFINITY; }
        s[ni][r] = v; mx = fmaxf(mx, v);
      }
      pm[r] = mx;
    }
#pragma unroll
    for (int o = 1; o < 16; o <<= 1)
#pragma unroll
      for (int r = 0; r < 4; ++r) pm[r] = fmaxf(pm[r], __shfl_xor(pm[r], o, 16));
    float fac[4], rs[4];
#pragma unroll
    for (int r = 0; r < 4; ++r) {
      float mn = fmaxf(mrow[r], pm[r]);
      fac[r] = __expf(mrow[r] - mn);
      mrow[r] = mn;
      float a = 0.f;
#pragma unroll
      for (int ni = 0; ni < 4; ++ni) { float p = __expf(s[ni][r] - mn); s[ni][r] = p; a += p; }
      rs[r] = a;
    }
#pragma unroll
    for (int o = 1; o < 16; o <<= 1)
#pragma unroll
      for (int r = 0; r < 4; ++r) rs[r] += __shfl_xor(rs[r], o, 16);
#pragma unroll
    for (int r = 0; r < 4; ++r) {
      lrow[r] = lrow[r] * fac[r] + rs[r];
#pragma unroll
      for (int ei = 0; ei < 4; ++ei) oacc[ei][r] *= fac[r];
    }
    // P -> LDS (wave-private; only lgkmcnt ordering needed, NO barrier)
#pragma unroll
    for (int ni = 0; ni < 4; ++ni)
#pragma unroll
      for (int r = 0; r < 4; ++r)
        U.a.Ps[w * 16 + (lane >> 4) * 4 + r][ni * 16 + (lane & 15)] = f2h(s[ni][r]);
    // O += P @ V  (VT read uses the same chunk-XOR swizzle)
#pragma unroll
    for (int ks = 0; ks < 2; ++ks) {
      half8 ap = ld8(&U.a.Ps[w * 16 + (lane & 15)][ks * 32 + (lane >> 4) * 8]);
#pragma unroll
      for (int ei = 0; ei < 4; ++ei) {
        int erow = ei * 16 + (lane & 15);
        int ccol = (((ks * 4 + (lane >> 4)) ^ (ei * 2 + ((lane & 15) >> 3))) << 3);
        half8 bv = ld8(&U.a.VTs[erow][ccol]);
        oacc[ei] = mfma16(ap, bv, oacc[ei]);
      }
    }
    __syncthreads();   // all reads of Ks/VTs done before next staging write
  }

  // ---- combine epilogue via MFMA: num = sq @ MpT^T ----
  // fill sqH (fp16 elu(Q)+1) + per-row sums
  {
    const int q = t >> 2, c0 = (t & 3) * 16;
    union { uint2 v; u16 s[4]; } qa;
    float partial = 0.f;
    union { uint4 v; u16 hh[8]; } o;
#pragma unroll
    for (int half = 0; half < 2; ++half) {
#pragma unroll
      for (int jj = 0; jj < 2; ++jj) {
        qa.v = *(const uint2*)&Qs[q][c0 + half * 8 + jj * 4];
#pragma unroll
        for (int k4 = 0; k4 < 4; ++k4) {
          float sv = elu1(h2f(qa.s[k4]));
          partial += sv;
          o.hh[jj * 4 + k4] = f2h(sv);
        }
      }
      *(uint4*)&U.b.sqH[q][c0 + half * 8] = o.v;
    }
    partial += __shfl_xor(partial, 1);
    partial += __shfl_xor(partial, 2);
    if ((t & 3) == 0) U.b.rowS[q] = partial;
  }
  // stage MpT tile (64 e x 64 d, fp16)
  const size_t mpb = (size_t)((n * 16 + h) * 16 + seg) * 4096;
#pragma unroll
  for (int p = 0; p < 2; ++p) {
    int e = p * 32 + (t >> 3), c = (t & 7) * 8;
    *(uint4*)&U.b.MpTs[e][c] = *(const uint4*)&MpT[mpb + e * 64 + c];
  }
  __syncthreads();

  f32x4 num[4] = {};
#pragma unroll
  for (int ks = 0; ks < 2; ++ks) {
    half8 asq = ld8(&U.b.sqH[w * 16 + (lane & 15)][ks * 32 + (lane >> 4) * 8]);
#pragma unroll
    for (int ni = 0; ni < 4; ++ni) {
      half8 bmp = ld8(&U.b.MpTs[ni * 16 + (lane & 15)][ks * 32 + (lane >> 4) * 8]);
      num[ni] = mfma16(asq, bmp, num[ni]);
    }
  }

  const float gb = 1.f / (1.f + __expf(-beta[0]));
  const size_t zb = (size_t)((n * 16 + h) * 16 + seg) * 64;
  const int g = lane >> 4;
  float rsv[4];
#pragma unroll
  for (int r = 0; r < 4; ++r) rsv[r] = U.b.rowS[w * 16 + g * 4 + r];
  // out row: l = qt*64 + w*16 + g*4 + r ; t_out = seg*512+h*32+(l>>4); c = (l&15)*64+e
  const size_t orow = ((size_t)(n * 8192 + seg * 512 + h * 32 + qt * 4 + w)) * 1024;
#pragma unroll
  for (int ni = 0; ni < 4; ++ni) {
    float z = Zpre[zb + ni * 16 + (lane & 15)];
#pragma unroll
    for (int r = 0; r < 4; ++r) {
      float am = num[ni][r] / (rsv[r] * z + 1e-6f);
      float loc = oacc[ni][r] / lrow[r];
      float val = gb * am + (1.f - gb) * loc;
      ao[orow + (size_t)(g * 4 + r) * 64 + ni * 16 + (lane & 15)] = f2h(val);
    }
  }
}

// ---------------- launch ----------------
extern "C" void kernel_launch(void* const* d_in, const int* in_sizes, int n_in,
                              void* d_out, int out_size, void* d_ws, size_t ws_size,
                              hipStream_t stream) {
  const float* x    = (const float*)d_in[0];
  const float* ln_g = (const float*)d_in[1];
  const float* ln_b = (const float*)d_in[2];
  const float* Wq   = (const float*)d_in[3];
  const float* bq   = (const float*)d_in[4];
  const float* Wk   = (const float*)d_in[5];
  const float* bk   = (const float*)d_in[6];
  const float* Wv   = (const float*)d_in[7];
  const float* bv   = (const float*)d_in[8];
  const float* Wo   = (const float*)d_in[9];
  const float* bo   = (const float*)d_in[10];
  const float* beta = (const float*)d_in[11];
  float* out = (float*)d_out;

  char* w = (char*)d_ws;
  u16*   xn    = (u16*)(w + 0);               // 32 MB
  u16*   qkv   = (u16*)(w + 33554432ull);     // 96 MB
  u16*   WqkvT = (u16*)(w + 134217728ull);    // 6 MB
  u16*   WoT   = (u16*)(w + 140509184ull);    // 2 MB
  float* bqkv  = (float*)(w + 142606336ull);  // 12 KB
  float* tab   = (float*)(w + 142618624ull);  // 2 MB
  float* Mseg  = (float*)(w + 144715776ull);  // 8 MB
  float* Zseg  = (float*)(w + 153104384ull);  // 128 KB
  u16*   MpT   = (u16*)(w + 153235456ull);    // 4 MB (transposed fp16 prefix)
  float* Zpre  = (float*)(w + 161624064ull);  // 128 KB
  u16*   ao    = (u16*)(w + 161755136ull);    // 32 MB

  prep_w<<<dim3(16, 16, 4), 256, 0, stream>>>(Wq, Wk, Wv, Wo, WqkvT, WoT);
  pack_bias<<<12, 256, 0, stream>>>(bq, bk, bv, bqkv);
  rope_table<<<1024, 256, 0, stream>>>(tab);
  lnorm<<<16384, 256, 0, stream>>>(x, ln_g, ln_b, xn);
  gemm_bt<true><<<dim3(128, 24), 256, 0, stream>>>(xn, WqkvT, bqkv, (void*)qkv, NT, QKVN, DD);
  rope_apply<<<16384, 256, 0, stream>>>(qkv, tab);
  segstats<<<512, 256, 0, stream>>>(qkv, Mseg, Zseg);
  prefix_k<<<32, 256, 0, stream>>>(Mseg, Zseg, MpT, Zpre);
  attn_seg<<<4096, 256, 0, stream>>>(qkv, MpT, Zpre, beta, ao);
  gemm_bt<false><<<dim3(128, 8), 256, 0, stream>>>(ao, WoT, bo, (void*)out, NT, DD, DD);
}

// Round 8
// 489.674 us; speedup vs baseline: 1.4319x; 1.0720x over previous
//
#include <hip/hip_runtime.h>
#include <hip/hip_bf16.h>
#include <math.h>

// ---- problem constants ----
// N=2 T=8192 D=1024 H=16 DQ=DV=64 S=16 L=512
#define NT 16384        // N*T rows
#define DD 1024
#define QKVN 3072

typedef unsigned short u16;
typedef _Float16 half8 __attribute__((ext_vector_type(8)));
typedef float f32x4 __attribute__((ext_vector_type(4)));

#define DEV static __device__ __forceinline__

DEV float h2f(u16 u) { _Float16 h; __builtin_memcpy(&h, &u, 2); return (float)h; }
DEV u16 f2h(float f) { _Float16 h = (_Float16)f; u16 u; __builtin_memcpy(&u, &h, 2); return u; }
DEV f32x4 mfma16(half8 a, half8 b, f32x4 c) {
  return __builtin_amdgcn_mfma_f32_16x16x32_f16(a, b, c, 0, 0, 0);
}
DEV half8 ld8(const u16* p) { return *(const half8*)p; }
DEV float elu1(float x) { return x > 0.f ? x + 1.f : __expf(x); }
DEV void gll16(const void* g, void* l) {
  __builtin_amdgcn_global_load_lds((const __attribute__((address_space(1))) void*)g,
                                   (__attribute__((address_space(3))) void*)l, 16, 0, 0);
}

// ---------------- weight transpose + cast (W[d][c] -> WT[c][d] fp16) ----------------
__global__ __launch_bounds__(256) void prep_w(const float* __restrict__ Wq,
    const float* __restrict__ Wk, const float* __restrict__ Wv,
    const float* __restrict__ Wo, u16* __restrict__ WqkvT, u16* __restrict__ WoT) {
  __shared__ float tile[64][65];
  const int mat = blockIdx.z;
  const float* src = mat == 0 ? Wq : mat == 1 ? Wk : mat == 2 ? Wv : Wo;
  const int d0 = blockIdx.x * 64, c0 = blockIdx.y * 64;
  const int t = threadIdx.x;
#pragma unroll
  for (int i = 0; i < 16; ++i) {
    int rl = (t >> 6) + i * 4;
    tile[rl][t & 63] = src[(size_t)(d0 + rl) * DD + c0 + (t & 63)];
  }
  __syncthreads();
  u16* dst = mat < 3 ? WqkvT + (size_t)mat * DD * DD : WoT;
#pragma unroll
  for (int i = 0; i < 16; ++i) {
    int cl = (t >> 6) + i * 4;
    dst[(size_t)(c0 + cl) * DD + d0 + (t & 63)] = f2h(tile[t & 63][cl]);
  }
}

__global__ void pack_bias(const float* __restrict__ bq, const float* __restrict__ bk,
                          const float* __restrict__ bv, float* __restrict__ bqkv) {
  int i = blockIdx.x * 256 + threadIdx.x;
  if (i < 1024) bqkv[i] = bq[i];
  else if (i < 2048) bqkv[i] = bk[i - 1024];
  else if (i < 3072) bqkv[i] = bv[i - 2048];
}

// ---------------- RoPE cos/sin table ----------------
__global__ __launch_bounds__(256) void rope_table(float* __restrict__ tab) {
  int idx = blockIdx.x * 256 + threadIdx.x;   // 8192*32
  int tp = idx >> 5, i = idx & 31;
  double inv = exp(-(double)i * (log(10000.0) / 32.0));
  double ang = (double)tp * inv;
  tab[idx * 2]     = (float)cos(ang);
  tab[idx * 2 + 1] = (float)sin(ang);
}

// ---------------- LayerNorm (fp32 in -> fp16 out) ----------------
__global__ __launch_bounds__(256) void lnorm(const float* __restrict__ x,
    const float* __restrict__ g, const float* __restrict__ b, u16* __restrict__ xn) {
  const int row = blockIdx.x, t = threadIdx.x;
  float4 v = ((const float4*)x)[(size_t)row * 256 + t];
  float s = v.x + v.y + v.z + v.w;
  float sq = v.x * v.x + v.y * v.y + v.z * v.z + v.w * v.w;
  for (int o = 32; o; o >>= 1) { s += __shfl_down(s, o); sq += __shfl_down(sq, o); }
  __shared__ float ps[4], pq[4];
  const int w = t >> 6, lane = t & 63;
  if (lane == 0) { ps[w] = s; pq[w] = sq; }
  __syncthreads();
  s = ps[0] + ps[1] + ps[2] + ps[3];
  sq = pq[0] + pq[1] + pq[2] + pq[3];
  float mu = s * (1.f / 1024.f);
  float var = sq * (1.f / 1024.f) - mu * mu;
  float rs = rsqrtf(var + 1e-5f);
  float4 gg = ((const float4*)g)[t], bb = ((const float4*)b)[t];
  float o0 = (v.x - mu) * rs * gg.x + bb.x;
  float o1 = (v.y - mu) * rs * gg.y + bb.y;
  float o2 = (v.z - mu) * rs * gg.z + bb.z;
  float o3 = (v.w - mu) * rs * gg.w + bb.w;
  uint2 u2;
  u2.x = (unsigned)f2h(o0) | ((unsigned)f2h(o1) << 16);
  u2.y = (unsigned)f2h(o2) | ((unsigned)f2h(o3) << 16);
  *(uint2*)&xn[(size_t)row * 1024 + t * 4] = u2;
}

// ---------------- GEMM 256x256, BK=64, 8 waves, 8-phase counted-vmcnt (T2+T3+T4+T5) ---
// C[M,N] = A[M,K] @ BT[N,K]^T + bias. fp16 in, fp32 accum.
// LDS 128KB dynamic: As[2buf][2kh][256][32] + Bs same. Chunk-XOR swizzle both sides.
// Phases per K-tile: (kh0,mh0)(kh0,mh1)(kh1,mh0)(kh1,mh1); 16 MFMA each.
// Staging units (tensor,kh) of NEXT tile issued one per phase; vmcnt(4) at ph0/ph2.
template <bool OUT_F16>
__global__ __launch_bounds__(512, 2) void gemm256(const u16* __restrict__ A,
    const u16* __restrict__ BT, const float* __restrict__ bias,
    void* __restrict__ C, int M, int N, int K, int gx) {
  extern __shared__ __align__(16) u16 lds[];
  u16* As = lds;            // [buf][kh][256][32] -> buf stride 16384, kh stride 8192
  u16* Bs = lds + 32768;
  const int t = threadIdx.x, lane = t & 63, w = t >> 6;
  const int wm = w >> 2, wn = w & 3;
  const int nwg = gridDim.x, bid = blockIdx.x;
  const int swz = (bid & 7) * (nwg >> 3) + (bid >> 3);   // bijective: nwg % 8 == 0
  const int bx = swz % gx, by = swz / gx;
  const int m0 = bx * 256, n0 = by * 256;
  const int NTK = K >> 6;
  const u16* Ab = A + (size_t)m0 * K;
  const u16* Bb = BT + (size_t)n0 * K;

  // frag read offsets (u16 units within a kh-plane)
  int aoff[8], boff[4];
#pragma unroll
  for (int mi = 0; mi < 8; ++mi) {
    int ra = wm * 128 + mi * 16 + (lane & 15);
    aoff[mi] = ra * 32 + (((lane >> 4) ^ ((ra >> 1) & 3)) * 8);
  }
#pragma unroll
  for (int ni = 0; ni < 4; ++ni) {
    int rb = wn * 64 + ni * 16 + (lane & 15);
    boff[ni] = rb * 32 + (((lane >> 4) ^ ((rb >> 1) & 3)) * 8);
  }
  // staging geometry: unit = (tensor,kh) plane [256][32]; wave w: 2 issues of 16 rows
  const int r1 = w * 16 + (lane >> 2);            // issue 0 rows 0..127
  const int r2 = 128 + r1;                        // issue 1 rows 128..255
  const int c1 = ((lane & 3) ^ ((r1 >> 1) & 3)) * 8;  // pre-swizzled global chunk
  const int c2 = ((lane & 3) ^ ((r2 >> 1) & 3)) * 8;
  const int l1 = (w * 16) * 32;                   // wave-uniform LDS base (u16)
  const int l2 = (128 + w * 16) * 32;

#define STAGE(Gb, Lp, kc)                                          \
  { gll16(&Gb[(size_t)r1 * K + (kc) + c1], (Lp) + l1);             \
    gll16(&Gb[(size_t)r2 * K + (kc) + c2], (Lp) + l2); }

  f32x4 acc[8][4] = {};
  // prologue: tile 0 units in canonical order A-k0, B-k0, A-k1, B-k1
  STAGE(Ab, As, 0);
  STAGE(Bb, Bs, 0);
  STAGE(Ab, As + 8192, 32);
  STAGE(Bb, Bs + 8192, 32);

  half8 af[4], bf[4];
  for (int kt = 0; kt < NTK; ++kt) {
    const int cur = kt & 1;
    u16* Ac = As + cur * 16384;
    u16* Bc = Bs + cur * 16384;
    u16* An = As + (cur ^ 1) * 16384;
    u16* Bn = Bs + (cur ^ 1) * 16384;
    const int kn = (kt + 1) * 64;
    const bool more = (kt + 1 < NTK);
    // ---- ph0: kh0, mh0 ----
    asm volatile("s_waitcnt vmcnt(4)" ::: "memory");   // A-k0,B-k0 of kt landed
    if (more) STAGE(Ab, An, kn);
    __builtin_amdgcn_s_barrier();
#pragma unroll
    for (int i = 0; i < 4; ++i) af[i] = ld8(Ac + aoff[i]);
#pragma unroll
    for (int i = 0; i < 4; ++i) bf[i] = ld8(Bc + boff[i]);
    __builtin_amdgcn_s_setprio(1);
#pragma unroll
    for (int mi = 0; mi < 4; ++mi)
#pragma unroll
      for (int ni = 0; ni < 4; ++ni)
        acc[mi][ni] = mfma16(af[mi], bf[ni], acc[mi][ni]);
    __builtin_amdgcn_s_setprio(0);
    __builtin_amdgcn_s_barrier();
    // ---- ph1: kh0, mh1 (reuse bf) ----
    if (more) STAGE(Bb, Bn, kn);
    __builtin_amdgcn_s_barrier();
#pragma unroll
    for (int i = 0; i < 4; ++i) af[i] = ld8(Ac + aoff[4 + i]);
    __builtin_amdgcn_s_setprio(1);
#pragma unroll
    for (int mi = 0; mi < 4; ++mi)
#pragma unroll
      for (int ni = 0; ni < 4; ++ni)
        acc[4 + mi][ni] = mfma16(af[mi], bf[ni], acc[4 + mi][ni]);
    __builtin_amdgcn_s_setprio(0);
    __builtin_amdgcn_s_barrier();
    // ---- ph2: kh1, mh0 ----
    if (more) { asm volatile("s_waitcnt vmcnt(4)" ::: "memory"); }   // A-k1,B-k1 of kt
    else      { asm volatile("s_waitcnt vmcnt(0)" ::: "memory"); }   // final drain
    if (more) STAGE(Ab, An + 8192, kn + 32);
    __builtin_amdgcn_s_barrier();
#pragma unroll
    for (int i = 0; i < 4; ++i) af[i] = ld8(Ac + 8192 + aoff[i]);
#pragma unroll
    for (int i = 0; i < 4; ++i) bf[i] = ld8(Bc + 8192 + boff[i]);
    __builtin_amdgcn_s_setprio(1);
#pragma unroll
    for (int mi = 0; mi < 4; ++mi)
#pragma unroll
      for (int ni = 0; ni < 4; ++ni)
        acc[mi][ni] = mfma16(af[mi], bf[ni], acc[mi][ni]);
    __builtin_amdgcn_s_setprio(0);
    __builtin_amdgcn_s_barrier();
    // ---- ph3: kh1, mh1 (reuse bf) ----
    if (more) STAGE(Bb, Bn + 8192, kn + 32);
    __builtin_amdgcn_s_barrier();
#pragma unroll
    for (int i = 0; i < 4; ++i) af[i] = ld8(Ac + 8192 + aoff[4 + i]);
    __builtin_amdgcn_s_setprio(1);
#pragma unroll
    for (int mi = 0; mi < 4; ++mi)
#pragma unroll
      for (int ni = 0; ni < 4; ++ni)
        acc[4 + mi][ni] = mfma16(af[mi], bf[ni], acc[4 + mi][ni]);
    __builtin_amdgcn_s_setprio(0);
    __builtin_amdgcn_s_barrier();
  }
#undef STAGE
  // epilogue: bias + store
  const int rg = lane >> 4, cl = lane & 15;
#pragma unroll
  for (int mi = 0; mi < 8; ++mi)
#pragma unroll
    for (int r = 0; r < 4; ++r) {
      size_t row = (size_t)(m0 + wm * 128 + mi * 16 + rg * 4 + r);
#pragma unroll
      for (int ni = 0; ni < 4; ++ni) {
        int col = n0 + wn * 64 + ni * 16 + cl;
        float v = acc[mi][ni][r] + bias[col];
        if (OUT_F16) ((u16*)C)[row * N + col] = f2h(v);
        else ((float*)C)[row * N + col] = v;
      }
    }
}

// ---------------- RoPE apply (in-place on q,k columns 0..2047 of qkv) ----------------
__global__ __launch_bounds__(256) void rope_apply(u16* __restrict__ qkv,
                                                  const float* __restrict__ tab) {
  const int row = blockIdx.x, t = threadIdx.x;
  const int c = t * 8;                 // 0..2047
  const int tp = row & 8191;
  const int d0 = c & 63;
  size_t off = (size_t)row * QKVN + c;
  union { uint4 v; u16 s[8]; } q;
  q.v = *(const uint4*)&qkv[off];
  float4 cs0 = *(const float4*)&tab[(tp * 32 + (d0 >> 1)) * 2];
  float4 cs1 = *(const float4*)&tab[(tp * 32 + (d0 >> 1)) * 2 + 4];
  float co[4] = {cs0.x, cs0.z, cs1.x, cs1.z};
  float si[4] = {cs0.y, cs0.w, cs1.y, cs1.w};
#pragma unroll
  for (int j = 0; j < 4; ++j) {
    float x0 = h2f(q.s[2 * j]), x1 = h2f(q.s[2 * j + 1]);
    q.s[2 * j]     = f2h(x0 * co[j] - x1 * si[j]);
    q.s[2 * j + 1] = f2h(x1 * co[j] + x0 * si[j]);
  }
  *(uint4*)&qkv[off] = q.v;
}

// ---------------- per-segment stats: MsegT[e][d] = sum_l v[l][e] sk[l][d]; Zseg[d] ----
__global__ __launch_bounds__(256) void segstats(const u16* __restrict__ qkv,
    float* __restrict__ MsegT, float* __restrict__ Zseg) {
  __shared__ float skL[128][64];
  __shared__ float vL[128][64];
  const int b = blockIdx.x;            // (n*16+h)*16+seg
  const int seg = b & 15, h = (b >> 4) & 15, n = b >> 8;
  const int t = threadIdx.x;
  const int d = t >> 2, e0 = (t & 3) * 16;
  float acc[16] = {};
  float zacc = 0.f;
  const size_t base = (size_t)(n * 8192 + seg * 512) * QKVN;
  for (int ch = 0; ch < 4; ++ch) {
#pragma unroll
    for (int p = 0; p < 4; ++p) {
      int r = (t >> 3) + 32 * p;
      int cs = (t & 7) * 8;
      size_t ro = base + (size_t)(ch * 128 + r) * QKVN + h * 64 + cs;
      union { uint4 v; u16 s[8]; } kk, vv;
      kk.v = *(const uint4*)&qkv[ro + 1024];
      vv.v = *(const uint4*)&qkv[ro + 2048];
#pragma unroll
      for (int j = 0; j < 8; ++j) {
        skL[r][cs + j] = elu1(h2f(kk.s[j]));
        vL[r][cs + j] = h2f(vv.s[j]);
      }
    }
    __syncthreads();
    for (int l = 0; l < 128; ++l) {
      float s = skL[l][d];
      zacc += s;
      const float4* vr = (const float4*)&vL[l][e0];
      float4 a0 = vr[0], a1 = vr[1], a2 = vr[2], a3 = vr[3];
      acc[0] += s * a0.x;  acc[1] += s * a0.y;  acc[2] += s * a0.z;  acc[3] += s * a0.w;
      acc[4] += s * a1.x;  acc[5] += s * a1.y;  acc[6] += s * a1.z;  acc[7] += s * a1.w;
      acc[8] += s * a2.x;  acc[9] += s * a2.y;  acc[10] += s * a2.z; acc[11] += s * a2.w;
      acc[12] += s * a3.x; acc[13] += s * a3.y; acc[14] += s * a3.z; acc[15] += s * a3.w;
    }
    __syncthreads();
  }
  if ((t & 3) == 0) Zseg[(size_t)b * 64 + d] = zacc;
  // transpose acc (thread holds M[d][e0..e0+15]) via LDS -> write MsegT[e][d] coalesced
  float* tr = &skL[0][0];   // reuse as [64][65]
#pragma unroll
  for (int j = 0; j < 16; ++j) tr[d * 65 + e0 + j] = acc[j];
  __syncthreads();
  const int e2 = t >> 2, d02 = (t & 3) * 16;
  float ov[16];
#pragma unroll
  for (int j = 0; j < 16; ++j) ov[j] = tr[(d02 + j) * 65 + e2];
  size_t mb = (size_t)b * 4096 + e2 * 64 + d02;
#pragma unroll
  for (int j4 = 0; j4 < 4; ++j4) {
    float4 o = {ov[j4 * 4], ov[j4 * 4 + 1], ov[j4 * 4 + 2], ov[j4 * 4 + 3]};
    *(float4*)&MsegT[mb + j4 * 4] = o;
  }
}

// ---------------- exclusive prefix over segments (coalesced, 128 blocks) ----------------
__global__ __launch_bounds__(256) void prefix_k(const float* __restrict__ MsegT,
    const float* __restrict__ Zseg, u16* __restrict__ MpT, float* __restrict__ Zpre) {
  const int nh = blockIdx.x >> 2, eg = blockIdx.x & 3;
  const int t = threadIdx.x;
  const int e = eg * 16 + (t >> 4), d4 = (t & 15) * 4;
  float4 acc = {0.f, 0.f, 0.f, 0.f};
  for (int s = 0; s < 16; ++s) {
    size_t idx = (size_t)(nh * 16 + s) * 4096 + e * 64 + d4;
    union { uint2 v; u16 hh[4]; } o;
    o.hh[0] = f2h(acc.x); o.hh[1] = f2h(acc.y);
    o.hh[2] = f2h(acc.z); o.hh[3] = f2h(acc.w);
    *(uint2*)&MpT[idx] = o.v;
    float4 m = *(const float4*)&MsegT[idx];
    acc.x += m.x; acc.y += m.y; acc.z += m.z; acc.w += m.w;
  }
  if (eg == 0 && t < 16) {
    float4 zac = {0.f, 0.f, 0.f, 0.f};
    for (int s = 0; s < 16; ++s) {
      size_t idx = (size_t)(nh * 16 + s) * 64 + t * 4;
      *(float4*)&Zpre[idx] = zac;
      float4 z = *(const float4*)&Zseg[idx];
      zac.x += z.x; zac.y += z.y; zac.z += z.z; zac.w += z.w;
    }
  }
}

// ---------------- fused per-segment attention + memory-read + combine ----------------
struct SmemA { u16 Ks[64][72]; u16 VTs[64][72]; u16 Ps[64][72]; };   // 27.6 KB
struct SmemB { u16 sqH[64][72]; u16 MpTs[64][72]; float rowS[64]; }; // 18.7 KB
union SmemU { SmemA a; SmemB b; };

__global__ __launch_bounds__(256, 3) void attn_seg(const u16* __restrict__ qkv,
    const u16* __restrict__ MpT, const float* __restrict__ Zpre,
    const float* __restrict__ beta, u16* __restrict__ ao) {
  __shared__ __align__(16) u16 Qs[64][72];
  __shared__ __align__(16) SmemU U;
  const int b = (blockIdx.x & 7) * 512 + (blockIdx.x >> 3);
  const int qt = b & 7, seg = (b >> 3) & 15, h = (b >> 7) & 15, n = b >> 11;
  const int t = threadIdx.x, lane = t & 63, w = t >> 6;

  const size_t qbase = (size_t)(n * 8192 + seg * 512 + qt * 64) * QKVN + h * 64;
#pragma unroll
  for (int p = 0; p < 2; ++p) {
    int r = p * 32 + (t >> 3), cs = (t & 7) * 8;
    *(uint4*)&Qs[r][cs] = *(const uint4*)&qkv[qbase + (size_t)r * QKVN + cs];
  }

  const int r0 = t >> 3;
  const int cs = (t & 7) * 8;
  const int vcol1 = (((w) ^ (t & 7)) << 3) | (r0 & 7);
  const int vcol2 = (((w + 4) ^ (t & 7)) << 3) | (r0 & 7);
  const size_t kbase = (size_t)(n * 8192 + seg * 512) * QKVN + h * 64 + cs;

  uint4 kk0, kk1, vv0, vv1;
  {
    size_t ro = kbase + (size_t)r0 * QKVN;
    kk0 = *(const uint4*)&qkv[ro + 1024];
    vv0 = *(const uint4*)&qkv[ro + 2048];
    kk1 = *(const uint4*)&qkv[ro + 32 * QKVN + 1024];
    vv1 = *(const uint4*)&qkv[ro + 32 * QKVN + 2048];
  }
  __syncthreads();
  half8 aq0 = ld8(&Qs[w * 16 + (lane & 15)][(lane >> 4) * 8]);
  half8 aq1 = ld8(&Qs[w * 16 + (lane & 15)][32 + (lane >> 4) * 8]);

  float mrow[4], lrow[4];
  f32x4 oacc[4] = {};
#pragma unroll
  for (int r = 0; r < 4; ++r) { mrow[r] = -INFINITY; lrow[r] = 0.f; }

  for (int mt = 0; mt <= qt; ++mt) {
    *(uint4*)&U.a.Ks[r0][cs] = kk0;
    *(uint4*)&U.a.Ks[r0 + 32][cs] = kk1;
    union { uint4 v; u16 s[8]; } u0, u1;
    u0.v = vv0; u1.v = vv1;
#pragma unroll
    for (int j = 0; j < 8; ++j) {
      U.a.VTs[cs + j][vcol1] = u0.s[j];
      U.a.VTs[cs + j][vcol2] = u1.s[j];
    }
    if (mt < qt) {
      size_t ro = kbase + (size_t)((mt + 1) * 64 + r0) * QKVN;
      kk0 = *(const uint4*)&qkv[ro + 1024];
      vv0 = *(const uint4*)&qkv[ro + 2048];
      kk1 = *(const uint4*)&qkv[ro + 32 * QKVN + 1024];
      vv1 = *(const uint4*)&qkv[ro + 32 * QKVN + 2048];
    }
    __syncthreads();

    f32x4 s[4] = {};
#pragma unroll
    for (int ni = 0; ni < 4; ++ni) {
      half8 b0 = ld8(&U.a.Ks[ni * 16 + (lane & 15)][(lane >> 4) * 8]);
      half8 b1 = ld8(&U.a.Ks[ni * 16 + (lane & 15)][32 + (lane >> 4) * 8]);
      s[ni] = mfma16(aq0, b0, s[ni]);
      s[ni] = mfma16(aq1, b1, s[ni]);
    }
    float pm[4];
#pragma unroll
    for (int r = 0; r < 4; ++r) {
      int ql = qt * 64 + w * 16 + (lane >> 4) * 4 + r;
      float mx = -INFINITY;
#pragma unroll
      for (int ni = 0; ni < 4; ++ni) {
        float v = s[ni][r] * 0.125f;
        if (mt == qt) { int ml = mt * 64 + ni * 16 + (lane & 15); if (ml > ql) v = -INFINITY; }
        s[ni][r] = v; mx = fmaxf(mx, v);
      }
      pm[r] = mx;
    }
#pragma unroll
    for (int o = 1; o < 16; o <<= 1)
#pragma unroll
      for (int r = 0; r < 4; ++r) pm[r] = fmaxf(pm[r], __shfl_xor(pm[r], o, 16));
    float fac[4], rs[4];
#pragma unroll
    for (int r = 0; r < 4; ++r) {
      float mn = fmaxf(mrow[r], pm[r]);
      fac[r] = __expf(mrow[r] - mn);
      mrow[r] = mn;
      float a = 0.f;
#pragma unroll
      for (int ni = 0; ni < 4; ++ni) { float p = __expf(s[ni][r] - mn); s[ni][r] = p; a += p; }
      rs[r] = a;
    }
#pragma unroll
    for (int o = 1; o < 16; o <<= 1)
#pragma unroll
      for (int r = 0; r < 4; ++r) rs[r] += __shfl_xor(rs[r], o, 16);
#pragma unroll
    for (int r = 0; r < 4; ++r) {
      lrow[r] = lrow[r] * fac[r] + rs[r];
#pragma unroll
      for (int ei = 0; ei < 4; ++ei) oacc[ei][r] *= fac[r];
    }
#pragma unroll
    for (int ni = 0; ni < 4; ++ni)
#pragma unroll
      for (int r = 0; r < 4; ++r)
        U.a.Ps[w * 16 + (lane >> 4) * 4 + r][ni * 16 + (lane & 15)] = f2h(s[ni][r]);
#pragma unroll
    for (int ks = 0; ks < 2; ++ks) {
      half8 ap = ld8(&U.a.Ps[w * 16 + (lane & 15)][ks * 32 + (lane >> 4) * 8]);
#pragma unroll
      for (int ei = 0; ei < 4; ++ei) {
        int erow = ei * 16 + (lane & 15);
        int ccol = (((ks * 4 + (lane >> 4)) ^ (ei * 2 + ((lane & 15) >> 3))) << 3);
        half8 bv = ld8(&U.a.VTs[erow][ccol]);
        oacc[ei] = mfma16(ap, bv, oacc[ei]);
      }
    }
    __syncthreads();
  }

  {
    const int q = t >> 2, c0 = (t & 3) * 16;
    union { uint2 v; u16 s[4]; } qa;
    float partial = 0.f;
    union { uint4 v; u16 hh[8]; } o;
#pragma unroll
    for (int half = 0; half < 2; ++half) {
#pragma unroll
      for (int jj = 0; jj < 2; ++jj) {
        qa.v = *(const uint2*)&Qs[q][c0 + half * 8 + jj * 4];
#pragma unroll
        for (int k4 = 0; k4 < 4; ++k4) {
          float sv = elu1(h2f(qa.s[k4]));
          partial += sv;
          o.hh[jj * 4 + k4] = f2h(sv);
        }
      }
      *(uint4*)&U.b.sqH[q][c0 + half * 8] = o.v;
    }
    partial += __shfl_xor(partial, 1);
    partial += __shfl_xor(partial, 2);
    if ((t & 3) == 0) U.b.rowS[q] = partial;
  }
  const size_t mpb = (size_t)((n * 16 + h) * 16 + seg) * 4096;
#pragma unroll
  for (int p = 0; p < 2; ++p) {
    int e = p * 32 + (t >> 3), c = (t & 7) * 8;
    *(uint4*)&U.b.MpTs[e][c] = *(const uint4*)&MpT[mpb + e * 64 + c];
  }
  __syncthreads();

  f32x4 num[4] = {};
#pragma unroll
  for (int ks = 0; ks < 2; ++ks) {
    half8 asq = ld8(&U.b.sqH[w * 16 + (lane & 15)][ks * 32 + (lane >> 4) * 8]);
#pragma unroll
    for (int ni = 0; ni < 4; ++ni) {
      half8 bmp = ld8(&U.b.MpTs[ni * 16 + (lane & 15)][ks * 32 + (lane >> 4) * 8]);
      num[ni] = mfma16(asq, bmp, num[ni]);
    }
  }

  const float gb = 1.f / (1.f + __expf(-beta[0]));
  const size_t zb = (size_t)((n * 16 + h) * 16 + seg) * 64;
  const int g = lane >> 4;
  float rsv[4];
#pragma unroll
  for (int r = 0; r < 4; ++r) rsv[r] = U.b.rowS[w * 16 + g * 4 + r];
  const size_t orow = ((size_t)(n * 8192 + seg * 512 + h * 32 + qt * 4 + w)) * 1024;
#pragma unroll
  for (int ni = 0; ni < 4; ++ni) {
    float z = Zpre[zb + ni * 16 + (lane & 15)];
#pragma unroll
    for (int r = 0; r < 4; ++r) {
      float am = num[ni][r] / (rsv[r] * z + 1e-6f);
      float loc = oacc[ni][r] / lrow[r];
      float val = gb * am + (1.f - gb) * loc;
      ao[orow + (size_t)(g * 4 + r) * 64 + ni * 16 + (lane & 15)] = f2h(val);
    }
  }
}

// ---------------- launch ----------------
extern "C" void kernel_launch(void* const* d_in, const int* in_sizes, int n_in,
                              void* d_out, int out_size, void* d_ws, size_t ws_size,
                              hipStream_t stream) {
  const float* x    = (const float*)d_in[0];
  const float* ln_g = (const float*)d_in[1];
  const float* ln_b = (const float*)d_in[2];
  const float* Wq   = (const float*)d_in[3];
  const float* bq   = (const float*)d_in[4];
  const float* Wk   = (const float*)d_in[5];
  const float* bk   = (const float*)d_in[6];
  const float* Wv   = (const float*)d_in[7];
  const float* bv   = (const float*)d_in[8];
  const float* Wo   = (const float*)d_in[9];
  const float* bo   = (const float*)d_in[10];
  const float* beta = (const float*)d_in[11];
  float* out = (float*)d_out;

  char* w = (char*)d_ws;
  u16*   xn    = (u16*)(w + 0);               // 32 MB
  u16*   qkv   = (u16*)(w + 33554432ull);     // 96 MB
  u16*   WqkvT = (u16*)(w + 134217728ull);    // 6 MB
  u16*   WoT   = (u16*)(w + 140509184ull);    // 2 MB
  float* bqkv  = (float*)(w + 142606336ull);  // 12 KB
  float* tab   = (float*)(w + 142618624ull);  // 2 MB
  float* MsegT = (float*)(w + 144715776ull);  // 8 MB (transposed [b][e][d])
  float* Zseg  = (float*)(w + 153104384ull);  // 128 KB
  u16*   MpT   = (u16*)(w + 153235456ull);    // 4 MB (fp16 exclusive prefix, [b][e][d])
  float* Zpre  = (float*)(w + 161624064ull);  // 128 KB
  u16*   ao    = (u16*)(w + 161755136ull);    // 32 MB

  hipFuncSetAttribute((const void*)&gemm256<true>,
                      hipFuncAttributeMaxDynamicSharedMemorySize, 131072);
  hipFuncSetAttribute((const void*)&gemm256<false>,
                      hipFuncAttributeMaxDynamicSharedMemorySize, 131072);

  prep_w<<<dim3(16, 16, 4), 256, 0, stream>>>(Wq, Wk, Wv, Wo, WqkvT, WoT);
  pack_bias<<<12, 256, 0, stream>>>(bq, bk, bv, bqkv);
  rope_table<<<1024, 256, 0, stream>>>(tab);
  lnorm<<<16384, 256, 0, stream>>>(x, ln_g, ln_b, xn);
  gemm256<true><<<768, 512, 131072, stream>>>(xn, WqkvT, bqkv, (void*)qkv,
                                              NT, QKVN, DD, 64);
  rope_apply<<<16384, 256, 0, stream>>>(qkv, tab);
  segstats<<<512, 256, 0, stream>>>(qkv, MsegT, Zseg);
  prefix_k<<<128, 256, 0, stream>>>(MsegT, Zseg, MpT, Zpre);
  attn_seg<<<4096, 256, 0, stream>>>(qkv, MpT, Zpre, beta, ao);
  gemm256<false><<<256, 512, 131072, stream>>>(ao, WoT, bo, (void*)out,
                                               NT, DD, DD, 64);
}